// Round 1
// 1816.109 us; speedup vs baseline: 2.8261x; 2.8261x over previous
//
#include <hip/hip_runtime.h>
#include <math.h>

// Problem constants (fixed by the reference)
constexpr int B_ = 32, T_ = 2048, E_ = 512, F_ = 512, KW = 7, H_ = 8;
constexpr float EPS_ = 1e-5f;

typedef unsigned short bfu;   // raw bf16 bits (internal workspace format)
typedef __attribute__((ext_vector_type(8))) unsigned short ushort8v;
typedef __attribute__((ext_vector_type(8))) short short8v;   // MFMA A/B frag (8 bf16)
typedef __attribute__((ext_vector_type(4))) float f32x4;     // MFMA C/D frag
typedef const __attribute__((address_space(1))) void* gp1_t;
typedef __attribute__((address_space(3))) void* lp3_t;

__device__ __forceinline__ float b2f(bfu u) {
    return __uint_as_float(((unsigned)u) << 16);
}
__device__ __forceinline__ bfu f2b(float f) {
    unsigned i = __float_as_uint(f);
    i += 0x7fffu + ((i >> 16) & 1u);   // round-to-nearest-even
    return (bfu)(i >> 16);
}

template <typename T> __device__ __forceinline__ void stv(T* p, size_t i, float v);
template <> __device__ __forceinline__ void stv<bfu>(bfu* p, size_t i, float v)   { p[i] = f2b(v); }
template <> __device__ __forceinline__ void stv<float>(float* p, size_t i, float v) { p[i] = v; }

// ---------------------------------------------------------------------------
__global__ void zero_kernel(float* p, int n) {
    int i = blockIdx.x * 256 + threadIdx.x;
    if (i < n) p[i] = 0.f;
}

// ---------------------------------------------------------------------------
// pe table over (b,e): pe[b,e] = sin/cos(b * div(e)) — only 32x512 values.
__global__ void pe_table(float* __restrict__ pe) {
    int i = blockIdx.x * 256 + threadIdx.x;   // 16384
    int b = i >> 9, e = i & 511;
    float div = expf(-(float)(e & ~1) * (logf(10000.0f) / (float)E_));
    float ang = (float)b * div;
    pe[i] = (e & 1) ? cosf(ang) : sinf(ang);
}

// x (B,T,E) fp32 + pe[b,e] -> bf16 (B,T,E). Fully coalesced, no transpose.
__global__ __launch_bounds__(256) void add_pe(const float* __restrict__ x,
                                              const float* __restrict__ pe,
                                              bfu* __restrict__ out) {
    size_t i = ((size_t)blockIdx.x * 256 + threadIdx.x) * 4;
    int e = (int)(i & 511);
    int b = (int)(i >> 20);                    // T_*E_ = 2^20 elems per batch
    float4 xv = *(const float4*)(x + i);
    float4 pv = *(const float4*)(pe + (b << 9) + e);
    ushort4 o = { f2b(xv.x + pv.x), f2b(xv.y + pv.y), f2b(xv.z + pv.z), f2b(xv.w + pv.w) };
    *(ushort4*)(out + i) = o;
}

// fp32 -> bf16 weight conversion (512x512 per call)
__global__ void w2b(const float* __restrict__ w, bfu* __restrict__ o) {
    int i = (blockIdx.x * 256 + threadIdx.x) * 4;
    float4 v = *(const float4*)(w + i);
    ushort4 u = { f2b(v.x), f2b(v.y), f2b(v.z), f2b(v.w) };
    *(ushort4*)(o + i) = u;
}

// ---------------------------------------------------------------------------
// LN stats: fp32 sum & sumsq per contiguous group of L bf16 elements.
__global__ __launch_bounds__(256) void ln_stats(const bfu* __restrict__ x,
                                                float* __restrict__ stats,
                                                int L, int slices) {
    int g = blockIdx.y, s = blockIdx.x;
    int chunk = L / slices;
    const ushort4* p = (const ushort4*)(x + (size_t)g * L + (size_t)s * chunk);
    int n4 = chunk >> 2;
    float sum = 0.f, sq = 0.f;
    for (int i = threadIdx.x; i < n4; i += 256) {
        ushort4 v = p[i];
        float a = b2f(v.x), b = b2f(v.y), c = b2f(v.z), d = b2f(v.w);
        sum += a + b + c + d;
        sq  += a * a + b * b + c * c + d * d;
    }
    #pragma unroll
    for (int off = 32; off > 0; off >>= 1) {
        sum += __shfl_down(sum, off, 64);
        sq  += __shfl_down(sq,  off, 64);
    }
    __shared__ float ss[8];
    int lane = threadIdx.x & 63, wid = threadIdx.x >> 6;
    if (lane == 0) { ss[wid] = sum; ss[4 + wid] = sq; }
    __syncthreads();
    if (threadIdx.x == 0) {
        atomicAdd(&stats[2 * g],     ss[0] + ss[1] + ss[2] + ss[3]);
        atomicAdd(&stats[2 * g + 1], ss[4] + ss[5] + ss[6] + ss[7]);
    }
}

__device__ __forceinline__ float ln_rstd(float sumsq, float mu, float invL) {
    float var = fmaxf(sumsq * invL - mu * mu, 0.f);
    return rsqrtf(var + EPS_);
}

// ---------------------------------------------------------------------------
// Depthwise conv in NHWC (B,T,F), K=7 pad 3, LN fused (per-b stats; padding
// zeros live in LN space, handled by skipping out-of-range taps).
// Thread: 8 consecutive f at one t -> ushort8 loads/stores, fully coalesced.
// Weights in LDS with 57-float chunk stride (25 mod 32 => conflict-free).
__global__ __launch_bounds__(256) void dwconv_nhwc(const bfu* __restrict__ x,
                                                   const float* __restrict__ stats,
                                                   const float* __restrict__ w,
                                                   const float* __restrict__ bias,
                                                   bfu* __restrict__ out) {
    __shared__ float ws[64 * 57];   // [f-chunk][(f&7)*7 + dt]
    int tid = threadIdx.x;
    int b = blockIdx.z;
    for (int i = tid; i < F_ * KW; i += 256) {
        int f = i / KW, dt = i - f * KW;
        ws[(f >> 3) * 57 + (f & 7) * 7 + dt] = w[i];
    }
    __syncthreads();
    const float invL = 1.0f / (float)(F_ * T_);
    float mu   = stats[2 * b] * invL;
    float rstd = ln_rstd(stats[2 * b + 1], mu, invL);
    int f0 = (tid & 63) * 8;
    int t  = blockIdx.x * 4 + (tid >> 6);
    const bfu* xb = x + (size_t)b * T_ * F_;
    const float* wc_ = &ws[(tid & 63) * 57];
    float acc[8];
    #pragma unroll
    for (int j = 0; j < 8; j++) acc[j] = bias[f0 + j];
    #pragma unroll
    for (int dt = 0; dt < KW; dt++) {
        int tt = t + dt - KW / 2;
        if (tt >= 0 && tt < T_) {
            ushort8v v = *(const ushort8v*)(xb + (size_t)tt * F_ + f0);
            #pragma unroll
            for (int j = 0; j < 8; j++)
                acc[j] += wc_[j * 7 + dt] * ((b2f(v[j]) - mu) * rstd);
        }
    }
    ushort8v o;
    #pragma unroll
    for (int j = 0; j < 8; j++) o[j] = f2b(acc[j]);
    *(ushort8v*)(out + ((size_t)b * T_ + t) * F_ + f0) = o;
}

// ---------------------------------------------------------------------------
// MFMA NT GEMM (m97 structure): out[r,m] = sum_k A[r,k]*Wb[m,k] + bias[m] (+res).
// A,Wb bf16 row-major K=512; 128x128 tile, BK=32, 4 waves, 4x4 16x16 frags/wave.
// Staging via global_load_lds width=16 into linear LDS [row][k] (64 B rows).
// A/B fragments use identical (lane>>4)*8+j k-mapping => k-permutation safe.
// C/D layout (m89-verified): col = lane&15, row = (lane>>4)*4 + reg.
// out_transpose=1: rows r=(t*32+b) written to out[b][t][m] (final fp32 (B,T,F)).
template <typename OutT>
__global__ __launch_bounds__(256) void gemm_mfma(const bfu* __restrict__ A,
                                                 const bfu* __restrict__ Wb,
                                                 const float* __restrict__ bias,
                                                 const bfu* res, OutT* out,
                                                 int out_transpose) {
    constexpr int Kd = 512;
    __shared__ bfu As[128 * 32];   // 8 KB, row stride 64 B
    __shared__ bfu Bs[128 * 32];
    // XCD-aware bijective swizzle: 2048 blocks, 8 XCDs, 256 per chunk.
    int id  = blockIdx.x;
    int swz = (id & 7) * 256 + (id >> 3);
    int m0 = (swz & 3) * 128;        // 4 m-tiles (fastest => A-panel sharing)
    int r0 = (swz >> 2) * 128;       // 512 r-tiles
    int tid  = threadIdx.x;
    int wave = tid >> 6, lane = tid & 63;
    int wr = (wave >> 1) * 64, wc = (wave & 1) * 64;
    int lg = lane >> 4,  lr = lane & 15;

    const char* Ab = (const char*)A  + (size_t)r0 * 1024;   // 1024 B per row
    const char* Bb = (const char*)Wb + (size_t)m0 * 1024;
    char* AsB = (char*)As;
    char* BsB = (char*)Bs;
    int rS = (wave << 4) + (lane >> 2);        // staging row (issue 0)
    int kb = (lane & 3) << 4;                  // 16 B chunk within 64 B row
    int ldsoff = wave << 10;                   // wave-uniform LDS base

    f32x4 acc[4][4];
    #pragma unroll
    for (int mi = 0; mi < 4; mi++)
        #pragma unroll
        for (int ni = 0; ni < 4; ni++)
            acc[mi][ni] = (f32x4){0.f, 0.f, 0.f, 0.f};

    const bfu* ApL = As + (wr + lr) * 32 + lg * 8;
    const bfu* BpL = Bs + (wc + lr) * 32 + lg * 8;

    for (int k0 = 0; k0 < Kd; k0 += 32) {
        size_t koff = (size_t)(k0 << 1);
        const char* a0 = Ab + (size_t)rS * 1024 + koff + kb;
        const char* b0 = Bb + (size_t)rS * 1024 + koff + kb;
        __builtin_amdgcn_global_load_lds((gp1_t)a0,           (lp3_t)(AsB + ldsoff),        16, 0, 0);
        __builtin_amdgcn_global_load_lds((gp1_t)(a0 + 65536), (lp3_t)(AsB + ldsoff + 4096), 16, 0, 0);
        __builtin_amdgcn_global_load_lds((gp1_t)b0,           (lp3_t)(BsB + ldsoff),        16, 0, 0);
        __builtin_amdgcn_global_load_lds((gp1_t)(b0 + 65536), (lp3_t)(BsB + ldsoff + 4096), 16, 0, 0);
        __syncthreads();   // drains vmcnt per __syncthreads semantics
        short8v a[4], bb[4];
        #pragma unroll
        for (int mi = 0; mi < 4; mi++) a[mi]  = *(const short8v*)(ApL + mi * 512);
        #pragma unroll
        for (int ni = 0; ni < 4; ni++) bb[ni] = *(const short8v*)(BpL + ni * 512);
        #pragma unroll
        for (int mi = 0; mi < 4; mi++)
            #pragma unroll
            for (int ni = 0; ni < 4; ni++)
                acc[mi][ni] = __builtin_amdgcn_mfma_f32_16x16x32_bf16(a[mi], bb[ni], acc[mi][ni], 0, 0, 0);
        __syncthreads();
    }

    #pragma unroll
    for (int ni = 0; ni < 4; ni++) {
        int m = m0 + wc + ni * 16 + lr;
        float bv = bias[m];
        #pragma unroll
        for (int mi = 0; mi < 4; mi++) {
            #pragma unroll
            for (int j = 0; j < 4; j++) {
                int r = r0 + wr + mi * 16 + lg * 4 + j;
                float v = acc[mi][ni][j] + bv;
                if (res) v += b2f(res[(size_t)r * 512 + m]);
                if (!out_transpose) {
                    stv(out, (size_t)r * 512 + m, v);
                } else {
                    int t = r >> 5, bb2 = r & 31;
                    stv(out, ((size_t)bb2 * T_ + t) * 512 + m, v);
                }
            }
        }
    }
}

// ---------------------------------------------------------------------------
// (B,T,F) -> (T,B,F): xa = raw copy, yln = LN-applied (per-b stats).
// F contiguous on both sides => coalesced; no tiled transpose needed.
__global__ __launch_bounds__(256) void bt2tb_ln(const bfu* __restrict__ x,
                                                const float* __restrict__ stats,
                                                bfu* __restrict__ xa,
                                                bfu* __restrict__ yln) {
    size_t i = ((size_t)blockIdx.x * 256 + threadIdx.x) * 8;
    int f = (int)(i & 511);
    size_t bt = i >> 9;
    int t = (int)(bt & 2047);
    int b = (int)(bt >> 11);
    const float invL = 1.0f / (float)(F_ * T_);
    float mu   = stats[2 * b] * invL;
    float rstd = ln_rstd(stats[2 * b + 1], mu, invL);
    ushort8v v = *(const ushort8v*)(x + i);
    size_t dst = (((size_t)t * B_ + b) << 9) + f;
    *(ushort8v*)(xa + dst) = v;
    ushort8v o;
    #pragma unroll
    for (int j = 0; j < 8; j++) o[j] = f2b((b2f(v[j]) - mu) * rstd);
    *(ushort8v*)(yln + dst) = o;
}

// LN apply over contiguous groups of (1<<shift) elems (used for final per-t LN).
__global__ __launch_bounds__(256) void ln_apply(const bfu* __restrict__ x,
                                                const float* __restrict__ stats,
                                                bfu* __restrict__ out,
                                                float invL, int shift) {
    size_t i = ((size_t)blockIdx.x * 256 + threadIdx.x) * 8;
    int g = (int)(i >> shift);
    float mu   = stats[2 * g] * invL;
    float rstd = ln_rstd(stats[2 * g + 1], mu, invL);
    ushort8v v = *(const ushort8v*)(x + i);
    ushort8v o;
    #pragma unroll
    for (int j = 0; j < 8; j++) o[j] = f2b((b2f(v[j]) - mu) * rstd);
    *(ushort8v*)(out + i) = o;
}

// ---------------------------------------------------------------------------
// Attention over the batch axis: one block per (t,h). Q,K,V (T,B,F) bf16.
__global__ __launch_bounds__(256) void attention(const bfu* __restrict__ Q,
                                                 const bfu* __restrict__ K,
                                                 const bfu* __restrict__ V,
                                                 bfu* __restrict__ O) {
    __shared__ float qs[32][65], ks[32][65], vs[32][65], ps[32][33];
    int t = blockIdx.x, h = blockIdx.y;
    int tid = threadIdx.x;
    size_t base = (size_t)t * B_ * F_ + (size_t)h * 64;
    for (int i = tid * 4; i < 32 * 64; i += 1024) {
        int bb = i >> 6, d = i & 63;
        size_t idx = base + (size_t)bb * F_ + d;
        ushort4 q4 = *(const ushort4*)(Q + idx);
        ushort4 k4 = *(const ushort4*)(K + idx);
        ushort4 v4 = *(const ushort4*)(V + idx);
        qs[bb][d] = b2f(q4.x); qs[bb][d + 1] = b2f(q4.y); qs[bb][d + 2] = b2f(q4.z); qs[bb][d + 3] = b2f(q4.w);
        ks[bb][d] = b2f(k4.x); ks[bb][d + 1] = b2f(k4.y); ks[bb][d + 2] = b2f(k4.z); ks[bb][d + 3] = b2f(k4.w);
        vs[bb][d] = b2f(v4.x); vs[bb][d + 1] = b2f(v4.y); vs[bb][d + 2] = b2f(v4.z); vs[bb][d + 3] = b2f(v4.w);
    }
    __syncthreads();
    int brow = tid >> 3;
    int c0   = (tid & 7) * 4;
    float sc0 = 0.f, sc1 = 0.f, sc2 = 0.f, sc3 = 0.f;
    for (int d = 0; d < 64; d++) {
        float qv = qs[brow][d];
        sc0 += qv * ks[c0 + 0][d];
        sc1 += qv * ks[c0 + 1][d];
        sc2 += qv * ks[c0 + 2][d];
        sc3 += qv * ks[c0 + 3][d];
    }
    ps[brow][c0 + 0] = sc0 * 0.125f;
    ps[brow][c0 + 1] = sc1 * 0.125f;
    ps[brow][c0 + 2] = sc2 * 0.125f;
    ps[brow][c0 + 3] = sc3 * 0.125f;
    __syncthreads();
    if (tid < 32) {
        float mx = -1e30f;
        for (int c = 0; c < 32; c++) mx = fmaxf(mx, ps[tid][c]);
        float sum = 0.f;
        for (int c = 0; c < 32; c++) { float e = expf(ps[tid][c] - mx); ps[tid][c] = e; sum += e; }
        float inv = 1.0f / sum;
        for (int c = 0; c < 32; c++) ps[tid][c] *= inv;
    }
    __syncthreads();
    int d0 = (tid & 7) * 8;
    float ov[8] = {};
    for (int c = 0; c < 32; c++) {
        float p = ps[brow][c];
        #pragma unroll
        for (int j = 0; j < 8; j++) ov[j] += p * vs[c][d0 + j];
    }
    #pragma unroll
    for (int j = 0; j < 8; j++)
        O[base + (size_t)brow * F_ + d0 + j] = f2b(ov[j]);
}

// ---------------------------------------------------------------------------
extern "C" void kernel_launch(void* const* d_in, const int* in_sizes, int n_in,
                              void* d_out, int out_size, void* d_ws, size_t ws_size,
                              hipStream_t stream) {
    const float* x     = (const float*)d_in[0];
    const float* dw1_w = (const float*)d_in[1];
    const float* dw1_b = (const float*)d_in[2];
    const float* pw1_w = (const float*)d_in[3];
    const float* pw1_b = (const float*)d_in[4];
    const float* dw2_w = (const float*)d_in[5];
    const float* dw2_b = (const float*)d_in[6];
    const float* pw2_w = (const float*)d_in[7];
    const float* pw2_b = (const float*)d_in[8];
    const float* wq = (const float*)d_in[9];   const float* bq = (const float*)d_in[10];
    const float* wk = (const float*)d_in[11];  const float* bk = (const float*)d_in[12];
    const float* wv = (const float*)d_in[13];  const float* bv = (const float*)d_in[14];
    const float* wp = (const float*)d_in[15];  const float* bp = (const float*)d_in[16];
    const float* ffw = (const float*)d_in[17]; const float* ffb = (const float*)d_in[18];
    float* out = (float*)d_out;

    const size_t SZ = (size_t)B_ * F_ * T_;   // 33,554,432 elems (64 MB bf16)
    const size_t WN = (size_t)F_ * F_;        // 262144 elems per weight matrix

    // Workspace: [stats 16KB][pe 64KB][7 bf16 weights 3.5MB] ... big bufs @ +4MB
    float* stats = (float*)d_ws;              // 4096 fp32
    float* peTab = stats + 4096;              // 16384 fp32
    bfu*   wBuf  = (bfu*)(peTab + 16384);
    bfu* wb_pw1 = wBuf + 0 * WN;
    bfu* wb_pw2 = wBuf + 1 * WN;
    bfu* wb_q   = wBuf + 2 * WN;
    bfu* wb_k   = wBuf + 3 * WN;
    bfu* wb_v   = wBuf + 4 * WN;
    bfu* wb_p   = wBuf + 5 * WN;
    bfu* wb_ff  = wBuf + 6 * WN;
    bfu* bufX = (bfu*)d_ws + (1 << 21);       // +4 MB: act (B,T,F); later Q
    bfu* bufC = bufX + SZ;                    // dwconv scratch; later xa (T,B,F)
    bfu* bufY = bufC + SZ;                    // yln (T,B,F); later attn O
    bfu* bufK = bufY + SZ;
    bfu* bufV = bufK + SZ;

    // weights -> bf16; pe table; pe-add (B,T,E stays layout-native now)
    pe_table<<<64, 256, 0, stream>>>(peTab);
    w2b<<<256, 256, 0, stream>>>(pw1_w, wb_pw1);
    w2b<<<256, 256, 0, stream>>>(pw2_w, wb_pw2);
    w2b<<<256, 256, 0, stream>>>(wq, wb_q);
    w2b<<<256, 256, 0, stream>>>(wk, wb_k);
    w2b<<<256, 256, 0, stream>>>(wv, wb_v);
    w2b<<<256, 256, 0, stream>>>(wp, wb_p);
    w2b<<<256, 256, 0, stream>>>(ffw, wb_ff);
    add_pe<<<32768, 256, 0, stream>>>(x, peTab, bufX);

    auto statsPerB = [&](const bfu* src) {
        zero_kernel<<<16, 256, 0, stream>>>(stats, 4096);
        ln_stats<<<dim3(64, B_), 256, 0, stream>>>(src, stats, F_ * T_, 64);
    };

    // conv1: x = pw1(dw1(ln(x0)))   [all in (B,T,F)]
    statsPerB(bufX);
    dwconv_nhwc<<<dim3(T_ / 4, 1, B_), 256, 0, stream>>>(bufX, stats, dw1_w, dw1_b, bufC);
    gemm_mfma<bfu><<<2048, 256, 0, stream>>>(bufC, wb_pw1, pw1_b, nullptr, bufX, 0);

    // conv loop (shared dw2/pw2 weights), residual fused into gemm epilogue
    for (int it = 0; it < 3; ++it) {
        statsPerB(bufX);
        dwconv_nhwc<<<dim3(T_ / 4, 1, B_), 256, 0, stream>>>(bufX, stats, dw2_w, dw2_b, bufC);
        gemm_mfma<bfu><<<2048, 256, 0, stream>>>(bufC, wb_pw2, pw2_b, bufX, bufX, 0);
    }

    // to (T,B,F): xa = x (bufC), yln = ln(x) (bufY)
    statsPerB(bufX);
    bt2tb_ln<<<16384, 256, 0, stream>>>(bufX, stats, bufC, bufY);

    // QKV projections (bufX dead -> reuse for Q); rows r = (t,b)
    gemm_mfma<bfu><<<2048, 256, 0, stream>>>(bufY, wb_q, bq, nullptr, bufX, 0);
    gemm_mfma<bfu><<<2048, 256, 0, stream>>>(bufY, wb_k, bk, nullptr, bufK, 0);
    gemm_mfma<bfu><<<2048, 256, 0, stream>>>(bufY, wb_v, bv, nullptr, bufV, 0);

    // attention across batch axis (yln dead -> bufY holds O)
    attention<<<dim3(T_, H_), 256, 0, stream>>>(bufX, bufK, bufV, bufY);

    // output projection + residual (xa in bufC): xnew -> bufK (K dead)
    gemm_mfma<bfu><<<2048, 256, 0, stream>>>(bufY, wb_p, bp, bufC, bufK, 0);

    // final LN per t over (B,F) = 16384 contiguous elems per group
    zero_kernel<<<16, 256, 0, stream>>>(stats, 4096);
    ln_stats<<<dim3(1, T_), 256, 0, stream>>>(bufK, stats, B_ * F_, 1);
    ln_apply<<<16384, 256, 0, stream>>>(bufK, stats, bufX, 1.0f / (float)(B_ * F_), 14);

    // FF gemm: A = ln(xnew), residual = xnew, fp32 (B,T,F) transposed output
    gemm_mfma<float><<<2048, 256, 0, stream>>>(bufX, wb_ff, ffb, bufK, out, 1);
}